// Round 1
// baseline (209.397 us; speedup 1.0000x reference)
//
#include <hip/hip_runtime.h>
#include <cstdint>
#include <cmath>

// ---- d_ws layout (4-byte words) ----
#define OFF_W1   0      // 32  u32: conv1 weight bits (27 bits: c*9+dy*3+dx)
#define OFF_T1   32     // 32  i32: conv1 popcount thresholds (pc <= thr -> bit 1)
#define OFF_W2   64     // 288 u32: conv2 weight bits [o][k] over 32 in-ch
#define OFF_T2   352    // 32  i32
#define OFF_W3   384    // 576 u32: conv3 weight bits [o][k]
#define OFF_T3   960    // 64  i32
#define OFF_WFC1 1024   // 256 u32: fc1 weight bits, 2 words per output (64 bits)
#define OFF_A4   1280   // 128 f32: h = clip(pc*a4 + c4, -1, 1)
#define OFF_C4   1408   // 128 f32
#define OFF_WF2  1536   // 256 f32: w_fc2 [2][128]
#define OFF_WF3  1792   // 512 f32: w_fc3 [4][128]
#define OFF_BN5  2304   // 4 f32: inv5[2], d5[2]
#define OFF_BN6  2308   // 8 f32: inv6[4], d6[4]
// total 2316 words = 9264 bytes

__device__ __forceinline__ int thr_int(double nterms, double g, double b, double m, double v) {
    double inv = g / sqrt(v + 1e-5);
    double t = m - b / inv;              // bit=1  <=>  c >= t   (inv > 0)
    double thr = floor((nterms - t) * 0.5);   // c = nterms - 2*pc  =>  pc <= thr
    if (thr < -2147000000.0) thr = -2147000000.0;
    if (thr >  2147000000.0) thr =  2147000000.0;
    return (int)thr;
}

__global__ void k_prep(const float* __restrict__ w1, const float* __restrict__ w2,
                       const float* __restrict__ w3, const float* __restrict__ wfc1,
                       const float* __restrict__ wfc2, const float* __restrict__ wfc3,
                       const float* __restrict__ bn1, const float* __restrict__ bn2,
                       const float* __restrict__ bn3, const float* __restrict__ bn4,
                       const float* __restrict__ bn5, const float* __restrict__ bn6,
                       unsigned int* __restrict__ ws) {
    int t = threadIdx.x;  // 256 threads, 1 block
    float* wsf = (float*)ws;
    int*   wsi = (int*)ws;
    if (t < 32) {
        unsigned int bits = 0;
        for (int j = 0; j < 27; ++j) bits |= (w1[t*27+j] >= 0.f ? 1u : 0u) << j;
        ws[OFF_W1 + t] = bits;
        wsi[OFF_T1 + t] = thr_int(27.0,  bn1[t], bn1[32+t], bn1[64+t], bn1[96+t]);
        wsi[OFF_T2 + t] = thr_int(288.0, bn2[t], bn2[32+t], bn2[64+t], bn2[96+t]);
    }
    for (int idx = t; idx < 288; idx += 256) {
        int o = idx / 9, k = idx - o*9;
        unsigned int bits = 0;
        for (int i = 0; i < 32; ++i) bits |= (w2[(o*32+i)*9 + k] >= 0.f ? 1u : 0u) << i;
        ws[OFF_W2 + idx] = bits;
    }
    for (int idx = t; idx < 576; idx += 256) {
        int o = idx / 9, k = idx - o*9;
        unsigned int bits = 0;
        for (int i = 0; i < 32; ++i) bits |= (w3[(o*32+i)*9 + k] >= 0.f ? 1u : 0u) << i;
        ws[OFF_W3 + idx] = bits;
    }
    if (t < 64) wsi[OFF_T3 + t] = thr_int(288.0, bn3[t], bn3[64+t], bn3[128+t], bn3[192+t]);
    if (t < 128) {
        unsigned int lo = 0, hi = 0;
        for (int j = 0; j < 32; ++j) lo |= (wfc1[t*64+j]    >= 0.f ? 1u : 0u) << j;
        for (int j = 0; j < 32; ++j) hi |= (wfc1[t*64+32+j] >= 0.f ? 1u : 0u) << j;
        ws[OFF_WFC1 + 2*t]     = lo;
        ws[OFF_WFC1 + 2*t + 1] = hi;
        float g = bn4[t], b = bn4[128+t], m = bn4[256+t], v = bn4[384+t];
        float inv = g / sqrtf(v + 1e-5f);
        wsf[OFF_A4 + t] = -2.f * inv;                 // c = 64 - 2*pc
        wsf[OFF_C4 + t] = (64.f - m) * inv + b;
    }
    for (int idx = t; idx < 256; idx += 256) wsf[OFF_WF2 + idx] = wfc2[idx];
    for (int idx = t; idx < 512; idx += 256) wsf[OFF_WF3 + idx] = wfc3[idx];
    if (t < 2) {
        float g = bn5[t], b = bn5[2+t], m = bn5[4+t], v = bn5[6+t];
        float inv = g / sqrtf(v + 1e-5f);
        wsf[OFF_BN5 + t]     = inv;
        wsf[OFF_BN5 + 2 + t] = b - m * inv;
    }
    if (t < 4) {
        float g = bn6[t], b = bn6[4+t], m = bn6[8+t], v = bn6[12+t];
        float inv = g / sqrtf(v + 1e-5f);
        wsf[OFF_BN6 + t]     = inv;
        wsf[OFF_BN6 + 4 + t] = b - m * inv;
    }
}

__global__ __launch_bounds__(64) void k_main(const float* __restrict__ x,
                                             const unsigned int* __restrict__ ws,
                                             float* __restrict__ out, int B) {
    __shared__ unsigned int s_inrow[66];   // [3][22] row bit-words (22 bits used)
    __shared__ unsigned int s_c1[400];     // conv1 output: [20][20], 32 och bits
    __shared__ unsigned int s_b1[100];     // pooled [10][10]
    __shared__ unsigned int s_b2[16];      // pooled [4][4]
    __shared__ float        s_h[128];      // fc1 activations

    const int tid = threadIdx.x;
    const int b   = blockIdx.x;
    const float* wsf = (const float*)ws;
    const int*   wsi = (const int*)ws;

    // ---- pack input signs: one row (c,y) per lane ----
    for (int r = tid; r < 66; r += 64) {
        int c = r / 22, y = r - c*22;
        const float2* p = (const float2*)(x + ((size_t)b*3 + c)*484 + (size_t)y*22);
        unsigned int bits = 0;
        #pragma unroll
        for (int j = 0; j < 11; ++j) {
            float2 v = p[j];
            bits |= (v.x >= 0.f ? 1u : 0u) << (2*j);
            bits |= (v.y >= 0.f ? 1u : 0u) << (2*j+1);
        }
        s_inrow[r] = bits;
    }
    __syncthreads();

    // ---- conv1 + BN sign -> packed och bits per position ----
    for (int pos = tid; pos < 400; pos += 64) {
        int y = pos / 20, xx = pos - y*20;
        unsigned int g = 0;
        #pragma unroll
        for (int c = 0; c < 3; ++c)
            #pragma unroll
            for (int dy = 0; dy < 3; ++dy)
                g |= ((s_inrow[c*22 + y + dy] >> xx) & 7u) << (c*9 + dy*3);
        unsigned int word = 0;
        for (int o = 0; o < 32; ++o) {
            int pc = __popc(g ^ ws[OFF_W1 + o]);
            word |= (pc <= wsi[OFF_T1 + o] ? 1u : 0u) << o;
        }
        s_c1[pos] = word;
    }
    __syncthreads();

    // ---- maxpool1 == OR of sign bits ----
    for (int p = tid; p < 100; p += 64) {
        int py = p / 10, px = p - py*10;
        int base = (2*py)*20 + 2*px;
        s_b1[p] = s_c1[base] | s_c1[base+1] | s_c1[base+20] | s_c1[base+21];
    }
    __syncthreads();

    // ---- conv2 + BN sign + pool2 (lane = one of 8x8 positions) ----
    {
        int y = tid >> 3, xx = tid & 7;
        unsigned int in9[9];
        #pragma unroll
        for (int dy = 0; dy < 3; ++dy)
            #pragma unroll
            for (int dx = 0; dx < 3; ++dx)
                in9[dy*3+dx] = s_b1[(y+dy)*10 + xx + dx];
        unsigned int word = 0;
        for (int o = 0; o < 32; ++o) {
            int s = 0;
            #pragma unroll
            for (int k = 0; k < 9; ++k)
                s += __popc(in9[k] ^ ws[OFF_W2 + o*9 + k]);
            word |= (s <= wsi[OFF_T2 + o] ? 1u : 0u) << o;
        }
        word |= __shfl_xor(word, 1);   // pool across x pairs
        word |= __shfl_xor(word, 8);   // pool across y pairs
        if ((tid & 9) == 0)            // x even, y even
            s_b2[(y>>1)*4 + (xx>>1)] = word;
    }
    __syncthreads();

    // ---- conv3 + BN sign + pool3 -> 64-bit feature via ballot (lane = och) ----
    unsigned long long b3;
    {
        unsigned int bb[16];
        #pragma unroll
        for (int i = 0; i < 16; ++i) bb[i] = s_b2[i];
        unsigned int w3r[9];
        #pragma unroll
        for (int k = 0; k < 9; ++k) w3r[k] = ws[OFF_W3 + tid*9 + k];
        int thr = wsi[OFF_T3 + tid];
        int anybit = 0;
        #pragma unroll
        for (int py = 0; py < 2; ++py)
            #pragma unroll
            for (int px = 0; px < 2; ++px) {
                int s = 0;
                #pragma unroll
                for (int dy = 0; dy < 3; ++dy)
                    #pragma unroll
                    for (int dx = 0; dx < 3; ++dx)
                        s += __popc(bb[(py+dy)*4 + px + dx] ^ w3r[dy*3+dx]);
                anybit |= (s <= thr) ? 1 : 0;
            }
        b3 = __ballot(anybit);
    }

    // ---- fc1: h = clip(pc*a4 + c4, -1, 1) ----
    {
        const unsigned long long* wfc1b = (const unsigned long long*)(ws + OFF_WFC1);
        for (int j = tid; j < 128; j += 64) {
            int pc = __popcll(b3 ^ wfc1b[j]);
            float pre = fmaf((float)pc, wsf[OFF_A4 + j], wsf[OFF_C4 + j]);
            s_h[j] = fminf(1.f, fmaxf(-1.f, pre));
        }
    }
    __syncthreads();

    // ---- fc2 (softmax) / fc3 (BN) ----
    {
        float h0 = s_h[tid], h1 = s_h[tid + 64];
        float part[6];
        #pragma unroll
        for (int j = 0; j < 2; ++j)
            part[j] = h0 * wsf[OFF_WF2 + j*128 + tid] + h1 * wsf[OFF_WF2 + j*128 + 64 + tid];
        #pragma unroll
        for (int j = 0; j < 4; ++j)
            part[2+j] = h0 * wsf[OFF_WF3 + j*128 + tid] + h1 * wsf[OFF_WF3 + j*128 + 64 + tid];
        for (int off = 32; off; off >>= 1) {
            #pragma unroll
            for (int j = 0; j < 6; ++j)
                part[j] += __shfl_xor(part[j], off);
        }
        if (tid < 6) {
            if (tid < 2) {
                float y0 = part[0]*wsf[OFF_BN5+0] + wsf[OFF_BN5+2];
                float y1 = part[1]*wsf[OFF_BN5+1] + wsf[OFF_BN5+3];
                float mx = fmaxf(y0, y1);
                float e0 = expf(y0 - mx), e1 = expf(y1 - mx);
                float r  = 1.f / (e0 + e1);
                out[(size_t)b*2 + tid] = (tid == 0 ? e0 : e1) * r;
            } else {
                int j = tid - 2;
                out[(size_t)B*2 + (size_t)b*4 + j] = part[2+j]*wsf[OFF_BN6+j] + wsf[OFF_BN6+4+j];
            }
        }
    }
}

extern "C" void kernel_launch(void* const* d_in, const int* in_sizes, int n_in,
                              void* d_out, int out_size, void* d_ws, size_t ws_size,
                              hipStream_t stream) {
    const float* x    = (const float*)d_in[0];
    const float* w1   = (const float*)d_in[1];
    const float* w2   = (const float*)d_in[2];
    const float* w3   = (const float*)d_in[3];
    const float* wfc1 = (const float*)d_in[4];
    const float* wfc2 = (const float*)d_in[5];
    const float* wfc3 = (const float*)d_in[6];
    const float* bn1  = (const float*)d_in[7];
    const float* bn2  = (const float*)d_in[8];
    const float* bn3  = (const float*)d_in[9];
    const float* bn4  = (const float*)d_in[10];
    const float* bn5  = (const float*)d_in[11];
    const float* bn6  = (const float*)d_in[12];
    unsigned int* ws  = (unsigned int*)d_ws;
    float* out        = (float*)d_out;
    int B = in_sizes[0] / 1452;   // 3*22*22

    k_prep<<<1, 256, 0, stream>>>(w1, w2, w3, wfc1, wfc2, wfc3,
                                  bn1, bn2, bn3, bn4, bn5, bn6, ws);
    k_main<<<B, 64, 0, stream>>>(x, ws, out, B);
}

// Round 2
// 203.742 us; speedup vs baseline: 1.0278x; 1.0278x over previous
//
#include <hip/hip_runtime.h>
#include <cstdint>
#include <cmath>

// ---- d_ws layout (4-byte words) ----
#define OFF_W1   0      // 32  u32: conv1 weight bits (27 bits: c*9+dy*3+dx)
#define OFF_T1   32     // 32  i32: conv1 popcount thresholds (pc <= thr -> bit 1)
#define OFF_W2   64     // 288 u32: conv2 weight bits [o][k] over 32 in-ch
#define OFF_T2   352    // 32  i32
#define OFF_W3   384    // 576 u32: conv3 weight bits [o][k]
#define OFF_T3   960    // 64  i32
#define OFF_WFC1 1024   // 256 u32: fc1 weight bits, 2 words per output (64 bits)
#define OFF_A4   1280   // 128 f32: h = clip(pc*a4 + c4, -1, 1)
#define OFF_C4   1408   // 128 f32
#define OFF_WF2  1536   // 256 f32: w_fc2 [2][128]
#define OFF_WF3  1792   // 512 f32: w_fc3 [4][128]
#define OFF_BN5  2304   // 4 f32: inv5[2], d5[2]
#define OFF_BN6  2308   // 8 f32: inv6[4], d6[4]

__device__ __forceinline__ int thr_int(double nterms, double g, double b, double m, double v) {
    double inv = g / sqrt(v + 1e-5);
    double t = m - b / inv;                   // bit=1  <=>  c >= t   (inv > 0)
    double thr = floor((nterms - t) * 0.5);   // c = nterms - 2*pc  =>  pc <= thr
    if (thr < -2147000000.0) thr = -2147000000.0;
    if (thr >  2147000000.0) thr =  2147000000.0;
    return (int)thr;
}

// 5 blocks x 256 threads. Coalesced global->LDS staging, then bit-pack from LDS.
// (R1: single-block k_prep was ~125us latency-bound on strided loads.)
__global__ void k_prep(const float* __restrict__ w1, const float* __restrict__ w2,
                       const float* __restrict__ w3, const float* __restrict__ wfc1,
                       const float* __restrict__ wfc2, const float* __restrict__ wfc3,
                       const float* __restrict__ bn1, const float* __restrict__ bn2,
                       const float* __restrict__ bn3, const float* __restrict__ bn4,
                       const float* __restrict__ bn5, const float* __restrict__ bn6,
                       unsigned int* __restrict__ ws) {
    __shared__ float stage[9216];
    int t = threadIdx.x;
    int blk = blockIdx.x;
    float* wsf = (float*)ws;
    int*   wsi = (int*)ws;

    if (blk == 0) {
        // w1 pack (864 floats -> LDS), T1, T2, bn5, bn6, wf2, wf3
        for (int i = t; i < 864; i += 256) stage[i] = w1[i];
        __syncthreads();
        if (t < 32) {
            unsigned int bits = 0;
            for (int j = 0; j < 27; ++j) bits |= (stage[t*27+j] >= 0.f ? 1u : 0u) << j;
            ws[OFF_W1 + t] = bits;
            wsi[OFF_T1 + t] = thr_int(27.0,  bn1[t], bn1[32+t], bn1[64+t], bn1[96+t]);
            wsi[OFF_T2 + t] = thr_int(288.0, bn2[t], bn2[32+t], bn2[64+t], bn2[96+t]);
        }
        for (int i = t; i < 256; i += 256) wsf[OFF_WF2 + i] = wfc2[i];
        for (int i = t; i < 512; i += 256) wsf[OFF_WF3 + i] = wfc3[i];
        if (t < 2) {
            float g = bn5[t], b = bn5[2+t], m = bn5[4+t], v = bn5[6+t];
            float inv = g / sqrtf(v + 1e-5f);
            wsf[OFF_BN5 + t]     = inv;
            wsf[OFF_BN5 + 2 + t] = b - m * inv;
        }
        if (t >= 4 && t < 8) {
            int j = t - 4;
            float g = bn6[j], b = bn6[4+j], m = bn6[8+j], v = bn6[12+j];
            float inv = g / sqrtf(v + 1e-5f);
            wsf[OFF_BN6 + j]     = inv;
            wsf[OFF_BN6 + 4 + j] = b - m * inv;
        }
    } else if (blk == 1) {
        // w2: 9216 floats, coalesced stage then pack 288 words
        for (int i = t; i < 9216; i += 256) stage[i] = w2[i];
        __syncthreads();
        for (int idx = t; idx < 288; idx += 256) {
            int o = idx / 9, k = idx - o*9;
            unsigned int bits = 0;
            for (int i = 0; i < 32; ++i)
                bits |= (stage[(o*32+i)*9 + k] >= 0.f ? 1u : 0u) << i;
            ws[OFF_W2 + idx] = bits;
        }
    } else if (blk == 2 || blk == 3) {
        // w3 half: 9216 floats each
        int base = (blk - 2) * 9216;
        for (int i = t; i < 9216; i += 256) stage[i] = w3[base + i];
        __syncthreads();
        for (int idx = t; idx < 288; idx += 256) {
            int o = idx / 9, k = idx - o*9;
            unsigned int bits = 0;
            for (int i = 0; i < 32; ++i)
                bits |= (stage[(o*32+i)*9 + k] >= 0.f ? 1u : 0u) << i;
            ws[OFF_W3 + base/32 + idx] = bits;   // base/32 = 0 or 288
        }
    } else {
        // wfc1 (8192 floats) stage + pack; A4/C4; T3
        for (int i = t; i < 8192; i += 256) stage[i] = wfc1[i];
        __syncthreads();
        if (t < 128) {
            unsigned int lo = 0, hi = 0;
            for (int j = 0; j < 32; ++j) lo |= (stage[t*64+j]    >= 0.f ? 1u : 0u) << j;
            for (int j = 0; j < 32; ++j) hi |= (stage[t*64+32+j] >= 0.f ? 1u : 0u) << j;
            ws[OFF_WFC1 + 2*t]     = lo;
            ws[OFF_WFC1 + 2*t + 1] = hi;
            float g = bn4[t], b = bn4[128+t], m = bn4[256+t], v = bn4[384+t];
            float inv = g / sqrtf(v + 1e-5f);
            wsf[OFF_A4 + t] = -2.f * inv;                 // c = 64 - 2*pc
            wsf[OFF_C4 + t] = (64.f - m) * inv + b;
        }
        if (t >= 128 && t < 192) {
            int j = t - 128;
            wsi[OFF_T3 + j] = thr_int(288.0, bn3[j], bn3[64+j], bn3[128+j], bn3[192+j]);
        }
    }
}

// 4 images per 256-thread block: one wave per image, wave-private LDS slice.
// (R1: 64-thread blocks hit the per-CU workgroup-slot limit -> 60% occupancy.)
#define WSTRIDE 712   // 66 + 400 + 100 + 16 + 128 words, padded to even
__global__ __launch_bounds__(256) void k_main(const float* __restrict__ x,
                                              const unsigned int* __restrict__ ws,
                                              float* __restrict__ out, int B) {
    __shared__ unsigned int s_u[4 * WSTRIDE];

    const int tid = threadIdx.x & 63;
    const int wid = threadIdx.x >> 6;
    const int b   = blockIdx.x * 4 + wid;
    const bool act = (b < B);
    const float* wsf = (const float*)ws;
    const int*   wsi = (const int*)ws;

    unsigned int* inrow = s_u + wid * WSTRIDE;   // [66]
    unsigned int* c1    = inrow + 66;            // [400]
    unsigned int* pb1   = c1 + 400;              // [100]
    unsigned int* pb2   = pb1 + 100;             // [16]
    float*        hbuf  = (float*)(pb2 + 16);    // [128]

    // ---- pack input signs: one row (c,y) per lane ----
    if (act) {
        for (int r = tid; r < 66; r += 64) {
            int c = r / 22, y = r - c*22;
            const float2* p = (const float2*)(x + ((size_t)b*3 + c)*484 + (size_t)y*22);
            unsigned int bits = 0;
            #pragma unroll
            for (int j = 0; j < 11; ++j) {
                float2 v = p[j];
                bits |= (v.x >= 0.f ? 1u : 0u) << (2*j);
                bits |= (v.y >= 0.f ? 1u : 0u) << (2*j+1);
            }
            inrow[r] = bits;
        }
    }
    __syncthreads();

    // ---- conv1 + BN sign -> packed och bits per position ----
    if (act) {
        for (int pos = tid; pos < 400; pos += 64) {
            int y = pos / 20, xx = pos - y*20;
            unsigned int g = 0;
            #pragma unroll
            for (int c = 0; c < 3; ++c)
                #pragma unroll
                for (int dy = 0; dy < 3; ++dy)
                    g |= ((inrow[c*22 + y + dy] >> xx) & 7u) << (c*9 + dy*3);
            unsigned int word = 0;
            #pragma unroll
            for (int o = 0; o < 32; ++o) {
                int pc = __popc(g ^ ws[OFF_W1 + o]);
                word |= (pc <= wsi[OFF_T1 + o] ? 1u : 0u) << o;
            }
            c1[pos] = word;
        }
    }
    __syncthreads();

    // ---- maxpool1 == OR of sign bits ----
    if (act) {
        for (int p = tid; p < 100; p += 64) {
            int py = p / 10, px = p - py*10;
            int base = (2*py)*20 + 2*px;
            pb1[p] = c1[base] | c1[base+1] | c1[base+20] | c1[base+21];
        }
    }
    __syncthreads();

    // ---- conv2 + BN sign + pool2 (lane = one of 8x8 positions) ----
    if (act) {
        int y = tid >> 3, xx = tid & 7;
        unsigned int in9[9];
        #pragma unroll
        for (int dy = 0; dy < 3; ++dy)
            #pragma unroll
            for (int dx = 0; dx < 3; ++dx)
                in9[dy*3+dx] = pb1[(y+dy)*10 + xx + dx];
        unsigned int word = 0;
        #pragma unroll
        for (int o = 0; o < 32; ++o) {
            int s = 0;
            #pragma unroll
            for (int k = 0; k < 9; ++k)
                s += __popc(in9[k] ^ ws[OFF_W2 + o*9 + k]);
            word |= (s <= wsi[OFF_T2 + o] ? 1u : 0u) << o;
        }
        word |= __shfl_xor(word, 1);   // pool across x pairs
        word |= __shfl_xor(word, 8);   // pool across y pairs
        if ((tid & 9) == 0)            // x even, y even
            pb2[(y>>1)*4 + (xx>>1)] = word;
    }
    __syncthreads();

    // ---- conv3 + BN sign + pool3 -> 64-bit feature via ballot (lane = och) ----
    unsigned long long b3 = 0;
    if (act) {
        unsigned int bb[16];
        #pragma unroll
        for (int i = 0; i < 16; ++i) bb[i] = pb2[i];
        unsigned int w3r[9];
        #pragma unroll
        for (int k = 0; k < 9; ++k) w3r[k] = ws[OFF_W3 + tid*9 + k];
        int thr = wsi[OFF_T3 + tid];
        int anybit = 0;
        #pragma unroll
        for (int py = 0; py < 2; ++py)
            #pragma unroll
            for (int px = 0; px < 2; ++px) {
                int s = 0;
                #pragma unroll
                for (int dy = 0; dy < 3; ++dy)
                    #pragma unroll
                    for (int dx = 0; dx < 3; ++dx)
                        s += __popc(bb[(py+dy)*4 + px + dx] ^ w3r[dy*3+dx]);
                anybit |= (s <= thr) ? 1 : 0;
            }
        b3 = __ballot(anybit);
    }

    // ---- fc1: h = clip(pc*a4 + c4, -1, 1) ----
    if (act) {
        const unsigned long long* wfc1b = (const unsigned long long*)(ws + OFF_WFC1);
        for (int j = tid; j < 128; j += 64) {
            int pc = __popcll(b3 ^ wfc1b[j]);
            float pre = fmaf((float)pc, wsf[OFF_A4 + j], wsf[OFF_C4 + j]);
            hbuf[j] = fminf(1.f, fmaxf(-1.f, pre));
        }
    }
    __syncthreads();

    // ---- fc2 (softmax) / fc3 (BN) ----
    if (act) {
        float h0 = hbuf[tid], h1 = hbuf[tid + 64];
        float part[6];
        #pragma unroll
        for (int j = 0; j < 2; ++j)
            part[j] = h0 * wsf[OFF_WF2 + j*128 + tid] + h1 * wsf[OFF_WF2 + j*128 + 64 + tid];
        #pragma unroll
        for (int j = 0; j < 4; ++j)
            part[2+j] = h0 * wsf[OFF_WF3 + j*128 + tid] + h1 * wsf[OFF_WF3 + j*128 + 64 + tid];
        #pragma unroll
        for (int off = 32; off; off >>= 1) {
            #pragma unroll
            for (int j = 0; j < 6; ++j)
                part[j] += __shfl_xor(part[j], off);
        }
        if (tid < 6) {
            if (tid < 2) {
                float y0 = part[0]*wsf[OFF_BN5+0] + wsf[OFF_BN5+2];
                float y1 = part[1]*wsf[OFF_BN5+1] + wsf[OFF_BN5+3];
                float mx = fmaxf(y0, y1);
                float e0 = expf(y0 - mx), e1 = expf(y1 - mx);
                float r  = 1.f / (e0 + e1);
                out[(size_t)b*2 + tid] = (tid == 0 ? e0 : e1) * r;
            } else {
                int j = tid - 2;
                out[(size_t)B*2 + (size_t)b*4 + j] = part[2+j]*wsf[OFF_BN6+j] + wsf[OFF_BN6+4+j];
            }
        }
    }
}

extern "C" void kernel_launch(void* const* d_in, const int* in_sizes, int n_in,
                              void* d_out, int out_size, void* d_ws, size_t ws_size,
                              hipStream_t stream) {
    const float* x    = (const float*)d_in[0];
    const float* w1   = (const float*)d_in[1];
    const float* w2   = (const float*)d_in[2];
    const float* w3   = (const float*)d_in[3];
    const float* wfc1 = (const float*)d_in[4];
    const float* wfc2 = (const float*)d_in[5];
    const float* wfc3 = (const float*)d_in[6];
    const float* bn1  = (const float*)d_in[7];
    const float* bn2  = (const float*)d_in[8];
    const float* bn3  = (const float*)d_in[9];
    const float* bn4  = (const float*)d_in[10];
    const float* bn5  = (const float*)d_in[11];
    const float* bn6  = (const float*)d_in[12];
    unsigned int* ws  = (unsigned int*)d_ws;
    float* out        = (float*)d_out;
    int B = in_sizes[0] / 1452;   // 3*22*22

    k_prep<<<5, 256, 0, stream>>>(w1, w2, w3, wfc1, wfc2, wfc3,
                                  bn1, bn2, bn3, bn4, bn5, bn6, ws);
    k_main<<<(B + 3) / 4, 256, 0, stream>>>(x, ws, out, B);
}

// Round 3
// 192.275 us; speedup vs baseline: 1.0891x; 1.0596x over previous
//
#include <hip/hip_runtime.h>
#include <cstdint>
#include <cmath>

// ---- d_ws layout (4-byte words) ----
// Thresholds are stored as negthr = -(thr+1):  pc <= thr  <=>  (pc + negthr) < 0
#define OFF_W1   0      // 32  u32: conv1 weight bits (27 bits: c*9+dy*3+dx)
#define OFF_T1   32     // 32  i32: conv1 negthr
#define OFF_W2   64     // 288 u32: conv2 weight bits [o][k] over 32 in-ch
#define OFF_T2   352    // 32  i32: conv2 negthr
#define OFF_W3   384    // 576 u32: conv3 weight bits [o][k]
#define OFF_T3   960    // 64  i32: conv3 negthr
#define OFF_WFC1 1024   // 256 u32: fc1 weight bits, 2 words per output (64 bits)
#define OFF_A4   1280   // 128 f32: h = clip(pc*a4 + c4, -1, 1)
#define OFF_C4   1408   // 128 f32
#define OFF_WF2  1536   // 256 f32: w_fc2 [2][128]
#define OFF_WF3  1792   // 512 f32: w_fc3 [4][128]
#define OFF_BN5  2304   // 4 f32: inv5[2], d5[2]
#define OFF_BN6  2308   // 8 f32: inv6[4], d6[4]

__device__ __forceinline__ int thr_neg(double nterms, double g, double b, double m, double v) {
    double inv = g / sqrt(v + 1e-5);
    double t = m - b / inv;                   // bit=1  <=>  c >= t   (inv > 0)
    double thr = floor((nterms - t) * 0.5);   // c = nterms - 2*pc  =>  pc <= thr
    if (thr < -2147000000.0) thr = -2147000000.0;
    if (thr >  2147000000.0) thr =  2147000000.0;
    return -((int)thr + 1);                   // sign(pc + negthr) == (pc <= thr)
}

// 5 blocks x 256 threads. Coalesced global->LDS staging, then bit-pack from LDS.
__global__ void k_prep(const float* __restrict__ w1, const float* __restrict__ w2,
                       const float* __restrict__ w3, const float* __restrict__ wfc1,
                       const float* __restrict__ wfc2, const float* __restrict__ wfc3,
                       const float* __restrict__ bn1, const float* __restrict__ bn2,
                       const float* __restrict__ bn3, const float* __restrict__ bn4,
                       const float* __restrict__ bn5, const float* __restrict__ bn6,
                       unsigned int* __restrict__ ws) {
    __shared__ float stage[9216];
    int t = threadIdx.x;
    int blk = blockIdx.x;
    float* wsf = (float*)ws;
    int*   wsi = (int*)ws;

    if (blk == 0) {
        for (int i = t; i < 864; i += 256) stage[i] = w1[i];
        __syncthreads();
        if (t < 32) {
            unsigned int bits = 0;
            for (int j = 0; j < 27; ++j) bits |= (stage[t*27+j] >= 0.f ? 1u : 0u) << j;
            ws[OFF_W1 + t] = bits;
            wsi[OFF_T1 + t] = thr_neg(27.0,  bn1[t], bn1[32+t], bn1[64+t], bn1[96+t]);
            wsi[OFF_T2 + t] = thr_neg(288.0, bn2[t], bn2[32+t], bn2[64+t], bn2[96+t]);
        }
        for (int i = t; i < 256; i += 256) wsf[OFF_WF2 + i] = wfc2[i];
        for (int i = t; i < 512; i += 256) wsf[OFF_WF3 + i] = wfc3[i];
        if (t < 2) {
            float g = bn5[t], b = bn5[2+t], m = bn5[4+t], v = bn5[6+t];
            float inv = g / sqrtf(v + 1e-5f);
            wsf[OFF_BN5 + t]     = inv;
            wsf[OFF_BN5 + 2 + t] = b - m * inv;
        }
        if (t >= 4 && t < 8) {
            int j = t - 4;
            float g = bn6[j], b = bn6[4+j], m = bn6[8+j], v = bn6[12+j];
            float inv = g / sqrtf(v + 1e-5f);
            wsf[OFF_BN6 + j]     = inv;
            wsf[OFF_BN6 + 4 + j] = b - m * inv;
        }
    } else if (blk == 1) {
        for (int i = t; i < 9216; i += 256) stage[i] = w2[i];
        __syncthreads();
        for (int idx = t; idx < 288; idx += 256) {
            int o = idx / 9, k = idx - o*9;
            unsigned int bits = 0;
            for (int i = 0; i < 32; ++i)
                bits |= (stage[(o*32+i)*9 + k] >= 0.f ? 1u : 0u) << i;
            ws[OFF_W2 + idx] = bits;
        }
    } else if (blk == 2 || blk == 3) {
        int base = (blk - 2) * 9216;
        for (int i = t; i < 9216; i += 256) stage[i] = w3[base + i];
        __syncthreads();
        for (int idx = t; idx < 288; idx += 256) {
            int o = idx / 9, k = idx - o*9;
            unsigned int bits = 0;
            for (int i = 0; i < 32; ++i)
                bits |= (stage[(o*32+i)*9 + k] >= 0.f ? 1u : 0u) << i;
            ws[OFF_W3 + base/32 + idx] = bits;   // base/32 = 0 or 288
        }
    } else {
        for (int i = t; i < 8192; i += 256) stage[i] = wfc1[i];
        __syncthreads();
        if (t < 128) {
            unsigned int lo = 0, hi = 0;
            for (int j = 0; j < 32; ++j) lo |= (stage[t*64+j]    >= 0.f ? 1u : 0u) << j;
            for (int j = 0; j < 32; ++j) hi |= (stage[t*64+32+j] >= 0.f ? 1u : 0u) << j;
            ws[OFF_WFC1 + 2*t]     = lo;
            ws[OFF_WFC1 + 2*t + 1] = hi;
            float g = bn4[t], b = bn4[128+t], m = bn4[256+t], v = bn4[384+t];
            float inv = g / sqrtf(v + 1e-5f);
            wsf[OFF_A4 + t] = -2.f * inv;                 // c = 64 - 2*pc
            wsf[OFF_C4 + t] = (64.f - m) * inv + b;
        }
        if (t >= 128 && t < 192) {
            int j = t - 128;
            wsi[OFF_T3 + j] = thr_neg(288.0, bn3[j], bn3[64+j], bn3[128+j], bn3[192+j]);
        }
    }
}

// 4 images per 256-thread block: one wave per image, wave-private LDS slice.
#define WSTRIDE 584   // 66 + 400 + 100 + 16, padded to even
__global__ __launch_bounds__(256) void k_main(const float* __restrict__ x,
                                              const unsigned int* __restrict__ ws,
                                              float* __restrict__ out, int B) {
    __shared__ unsigned int s_u[4 * WSTRIDE];

    const int tid = threadIdx.x & 63;
    const int wid = threadIdx.x >> 6;
    const int b   = blockIdx.x * 4 + wid;
    const bool act = (b < B);
    const float* wsf = (const float*)ws;
    const int*   wsi = (const int*)ws;

    unsigned int* inrow = s_u + wid * WSTRIDE;   // [66]
    unsigned int* c1    = inrow + 66;            // [400]
    unsigned int* pb1   = c1 + 400;              // [100]
    unsigned int* pb2   = pb1 + 100;             // [16]

    // ---- pack input signs: one row (c,y) per lane ----
    if (act) {
        for (int r = tid; r < 66; r += 64) {
            int c = r / 22, y = r - c*22;
            const float2* p = (const float2*)(x + ((size_t)b*3 + c)*484 + (size_t)y*22);
            unsigned int bits = 0;
            #pragma unroll
            for (int j = 0; j < 11; ++j) {
                float2 v = p[j];
                bits |= (v.x >= 0.f ? 1u : 0u) << (2*j);
                bits |= (v.y >= 0.f ? 1u : 0u) << (2*j+1);
            }
            inrow[r] = bits;
        }
    }
    __syncthreads();

    // ---- conv1 + BN sign: 3 VALU per (pos,och): xor, bcnt(acc=negthr), alignbit ----
    if (act) {
        for (int pos = tid; pos < 400; pos += 64) {
            int y = pos / 20, xx = pos - y*20;
            unsigned int g = 0;
            #pragma unroll
            for (int c = 0; c < 3; ++c)
                #pragma unroll
                for (int dy = 0; dy < 3; ++dy)
                    g |= ((inrow[c*22 + y + dy] >> xx) & 7u) << (c*9 + dy*3);
            unsigned int word = 0;
            #pragma unroll
            for (int o = 31; o >= 0; --o) {
                unsigned int s = (unsigned int)(__popc(g ^ ws[OFF_W1 + o]) + wsi[OFF_T1 + o]);
                word = __builtin_amdgcn_alignbit(word, s, 31);  // word=(word<<1)|(s>>31)
            }
            c1[pos] = word;
        }
    }
    __syncthreads();

    // ---- maxpool1 == OR of sign bits ----
    if (act) {
        for (int p = tid; p < 100; p += 64) {
            int py = p / 10, px = p - py*10;
            int base = (2*py)*20 + 2*px;
            pb1[p] = c1[base] | c1[base+1] | c1[base+20] | c1[base+21];
        }
    }
    __syncthreads();

    // ---- conv2 + BN sign + pool2 (lane = one of 8x8 positions) ----
    if (act) {
        int y = tid >> 3, xx = tid & 7;
        unsigned int in9[9];
        #pragma unroll
        for (int dy = 0; dy < 3; ++dy)
            #pragma unroll
            for (int dx = 0; dx < 3; ++dx)
                in9[dy*3+dx] = pb1[(y+dy)*10 + xx + dx];
        unsigned int word = 0;
        #pragma unroll
        for (int o = 31; o >= 0; --o) {
            int s = wsi[OFF_T2 + o];
            #pragma unroll
            for (int k = 0; k < 9; ++k)
                s += __popc(in9[k] ^ ws[OFF_W2 + o*9 + k]);
            word = __builtin_amdgcn_alignbit(word, (unsigned int)s, 31);
        }
        word |= __shfl_xor(word, 1);   // pool across x pairs
        word |= __shfl_xor(word, 8);   // pool across y pairs
        if ((tid & 9) == 0)            // x even, y even
            pb2[(y>>1)*4 + (xx>>1)] = word;
    }
    __syncthreads();

    // ---- conv3 + BN sign + pool3 -> 64-bit feature via ballot (lane = och) ----
    // OR of sign bits == sign bit of OR.
    unsigned long long b3 = 0;
    {
        unsigned int bb[16];
        #pragma unroll
        for (int i = 0; i < 16; ++i) bb[i] = pb2[i];
        unsigned int w3r[9];
        #pragma unroll
        for (int k = 0; k < 9; ++k) w3r[k] = ws[OFF_W3 + tid*9 + k];
        int negt = wsi[OFF_T3 + tid];
        unsigned int oracc = 0;
        #pragma unroll
        for (int py = 0; py < 2; ++py)
            #pragma unroll
            for (int px = 0; px < 2; ++px) {
                int s = negt;
                #pragma unroll
                for (int dy = 0; dy < 3; ++dy)
                    #pragma unroll
                    for (int dx = 0; dx < 3; ++dx)
                        s += __popc(bb[(py+dy)*4 + px + dx] ^ w3r[dy*3+dx]);
                oracc |= (unsigned int)s;
            }
        b3 = __ballot((int)oracc < 0);
    }

    // ---- fc1 in registers (outputs tid, tid+64 consumed by the same lane) ----
    float h0, h1;
    {
        const unsigned long long* wfc1b = (const unsigned long long*)(ws + OFF_WFC1);
        int pc0 = __popcll(b3 ^ wfc1b[tid]);
        int pc1 = __popcll(b3 ^ wfc1b[tid + 64]);
        float p0 = fmaf((float)pc0, wsf[OFF_A4 + tid],      wsf[OFF_C4 + tid]);
        float p1 = fmaf((float)pc1, wsf[OFF_A4 + tid + 64], wsf[OFF_C4 + tid + 64]);
        h0 = fminf(1.f, fmaxf(-1.f, p0));
        h1 = fminf(1.f, fmaxf(-1.f, p1));
    }

    // ---- fc2 (softmax) / fc3 (BN) ----
    if (act) {
        float part[6];
        #pragma unroll
        for (int j = 0; j < 2; ++j)
            part[j] = h0 * wsf[OFF_WF2 + j*128 + tid] + h1 * wsf[OFF_WF2 + j*128 + 64 + tid];
        #pragma unroll
        for (int j = 0; j < 4; ++j)
            part[2+j] = h0 * wsf[OFF_WF3 + j*128 + tid] + h1 * wsf[OFF_WF3 + j*128 + 64 + tid];
        #pragma unroll
        for (int off = 32; off; off >>= 1) {
            #pragma unroll
            for (int j = 0; j < 6; ++j)
                part[j] += __shfl_xor(part[j], off);
        }
        if (tid < 6) {
            if (tid < 2) {
                float y0 = part[0]*wsf[OFF_BN5+0] + wsf[OFF_BN5+2];
                float y1 = part[1]*wsf[OFF_BN5+1] + wsf[OFF_BN5+3];
                float mx = fmaxf(y0, y1);
                float e0 = expf(y0 - mx), e1 = expf(y1 - mx);
                float r  = 1.f / (e0 + e1);
                out[(size_t)b*2 + tid] = (tid == 0 ? e0 : e1) * r;
            } else {
                int j = tid - 2;
                out[(size_t)B*2 + (size_t)b*4 + j] = part[2+j]*wsf[OFF_BN6+j] + wsf[OFF_BN6+4+j];
            }
        }
    }
}

extern "C" void kernel_launch(void* const* d_in, const int* in_sizes, int n_in,
                              void* d_out, int out_size, void* d_ws, size_t ws_size,
                              hipStream_t stream) {
    const float* x    = (const float*)d_in[0];
    const float* w1   = (const float*)d_in[1];
    const float* w2   = (const float*)d_in[2];
    const float* w3   = (const float*)d_in[3];
    const float* wfc1 = (const float*)d_in[4];
    const float* wfc2 = (const float*)d_in[5];
    const float* wfc3 = (const float*)d_in[6];
    const float* bn1  = (const float*)d_in[7];
    const float* bn2  = (const float*)d_in[8];
    const float* bn3  = (const float*)d_in[9];
    const float* bn4  = (const float*)d_in[10];
    const float* bn5  = (const float*)d_in[11];
    const float* bn6  = (const float*)d_in[12];
    unsigned int* ws  = (unsigned int*)d_ws;
    float* out        = (float*)d_out;
    int B = in_sizes[0] / 1452;   // 3*22*22

    k_prep<<<5, 256, 0, stream>>>(w1, w2, w3, wfc1, wfc2, wfc3,
                                  bn1, bn2, bn3, bn4, bn5, bn6, ws);
    k_main<<<(B + 3) / 4, 256, 0, stream>>>(x, ws, out, B);
}

// Round 4
// 189.972 us; speedup vs baseline: 1.1023x; 1.0121x over previous
//
#include <hip/hip_runtime.h>
#include <cstdint>
#include <cmath>

// ---- d_ws layout (4-byte words) ----
// Thresholds are stored as negthr = -(thr+1):  pc <= thr  <=>  (pc + negthr) < 0
#define OFF_W1   0      // 32  u32: conv1 weight bits (27 bits: c*9+dy*3+dx)
#define OFF_T1   32     // 32  i32: conv1 negthr
#define OFF_W2   64     // 288 u32: conv2 weight bits [o][k] over 32 in-ch
#define OFF_T2   352    // 32  i32: conv2 negthr
#define OFF_W3   384    // 576 u32: conv3 weight bits [o][k]
#define OFF_T3   960    // 64  i32: conv3 negthr
#define OFF_WFC1 1024   // 256 u32: fc1 weight bits, 2 words per output (64 bits)
#define OFF_A4   1280   // 128 f32: h = clip(pc*a4 + c4, -1, 1)
#define OFF_C4   1408   // 128 f32
#define OFF_WF2  1536   // 256 f32: w_fc2 [2][128]
#define OFF_WF3  1792   // 512 f32: w_fc3 [4][128]
#define OFF_BN5  2304   // 4 f32: inv5[2], d5[2]
#define OFF_BN6  2308   // 8 f32: inv6[4], d6[4]

__device__ __forceinline__ int thr_neg(double nterms, double g, double b, double m, double v) {
    double inv = g / sqrt(v + 1e-5);
    double t = m - b / inv;                   // bit=1  <=>  c >= t   (inv > 0)
    double thr = floor((nterms - t) * 0.5);   // c = nterms - 2*pc  =>  pc <= thr
    if (thr < -2147000000.0) thr = -2147000000.0;
    if (thr >  2147000000.0) thr =  2147000000.0;
    return -((int)thr + 1);                   // sign(pc + negthr) == (pc <= thr)
}

// 5 blocks x 256 threads. Coalesced global->LDS staging, then bit-pack from LDS.
__global__ void k_prep(const float* __restrict__ w1, const float* __restrict__ w2,
                       const float* __restrict__ w3, const float* __restrict__ wfc1,
                       const float* __restrict__ wfc2, const float* __restrict__ wfc3,
                       const float* __restrict__ bn1, const float* __restrict__ bn2,
                       const float* __restrict__ bn3, const float* __restrict__ bn4,
                       const float* __restrict__ bn5, const float* __restrict__ bn6,
                       unsigned int* __restrict__ ws) {
    __shared__ float stage[9216];
    int t = threadIdx.x;
    int blk = blockIdx.x;
    float* wsf = (float*)ws;
    int*   wsi = (int*)ws;

    if (blk == 0) {
        for (int i = t; i < 864; i += 256) stage[i] = w1[i];
        __syncthreads();
        if (t < 32) {
            unsigned int bits = 0;
            for (int j = 0; j < 27; ++j) bits |= (stage[t*27+j] >= 0.f ? 1u : 0u) << j;
            ws[OFF_W1 + t] = bits;
            wsi[OFF_T1 + t] = thr_neg(27.0,  bn1[t], bn1[32+t], bn1[64+t], bn1[96+t]);
            wsi[OFF_T2 + t] = thr_neg(288.0, bn2[t], bn2[32+t], bn2[64+t], bn2[96+t]);
        }
        for (int i = t; i < 256; i += 256) wsf[OFF_WF2 + i] = wfc2[i];
        for (int i = t; i < 512; i += 256) wsf[OFF_WF3 + i] = wfc3[i];
        if (t < 2) {
            float g = bn5[t], b = bn5[2+t], m = bn5[4+t], v = bn5[6+t];
            float inv = g / sqrtf(v + 1e-5f);
            wsf[OFF_BN5 + t]     = inv;
            wsf[OFF_BN5 + 2 + t] = b - m * inv;
        }
        if (t >= 4 && t < 8) {
            int j = t - 4;
            float g = bn6[j], b = bn6[4+j], m = bn6[8+j], v = bn6[12+j];
            float inv = g / sqrtf(v + 1e-5f);
            wsf[OFF_BN6 + j]     = inv;
            wsf[OFF_BN6 + 4 + j] = b - m * inv;
        }
    } else if (blk == 1) {
        for (int i = t; i < 9216; i += 256) stage[i] = w2[i];
        __syncthreads();
        for (int idx = t; idx < 288; idx += 256) {
            int o = idx / 9, k = idx - o*9;
            unsigned int bits = 0;
            for (int i = 0; i < 32; ++i)
                bits |= (stage[(o*32+i)*9 + k] >= 0.f ? 1u : 0u) << i;
            ws[OFF_W2 + idx] = bits;
        }
    } else if (blk == 2 || blk == 3) {
        int base = (blk - 2) * 9216;
        for (int i = t; i < 9216; i += 256) stage[i] = w3[base + i];
        __syncthreads();
        for (int idx = t; idx < 288; idx += 256) {
            int o = idx / 9, k = idx - o*9;
            unsigned int bits = 0;
            for (int i = 0; i < 32; ++i)
                bits |= (stage[(o*32+i)*9 + k] >= 0.f ? 1u : 0u) << i;
            ws[OFF_W3 + base/32 + idx] = bits;   // base/32 = 0 or 288
        }
    } else {
        for (int i = t; i < 8192; i += 256) stage[i] = wfc1[i];
        __syncthreads();
        if (t < 128) {
            unsigned int lo = 0, hi = 0;
            for (int j = 0; j < 32; ++j) lo |= (stage[t*64+j]    >= 0.f ? 1u : 0u) << j;
            for (int j = 0; j < 32; ++j) hi |= (stage[t*64+32+j] >= 0.f ? 1u : 0u) << j;
            ws[OFF_WFC1 + 2*t]     = lo;
            ws[OFF_WFC1 + 2*t + 1] = hi;
            float g = bn4[t], b = bn4[128+t], m = bn4[256+t], v = bn4[384+t];
            float inv = g / sqrtf(v + 1e-5f);
            wsf[OFF_A4 + t] = -2.f * inv;                 // c = 64 - 2*pc
            wsf[OFF_C4 + t] = (64.f - m) * inv + b;
        }
        if (t >= 128 && t < 192) {
            int j = t - 128;
            wsi[OFF_T3 + j] = thr_neg(288.0, bn3[j], bn3[64+j], bn3[128+j], bn3[192+j]);
        }
    }
}

// 4 images per 256-thread block: one wave per image, wave-private LDS slice.
// All inter-stage deps are wave-internal (same-wave DS ops execute in order on
// CDNA) -> no hardware barriers needed; wave_barrier() is a compiler
// code-motion fence only (0 instructions). R3's __syncthreads forced 4
// unrelated waves into lockstep + drained vmcnt/lgkmcnt at every layer.
#define WSTRIDE 584   // 66 + 400 + 100 + 16, padded to even
__global__ __launch_bounds__(256) void k_main(const float* __restrict__ x,
                                              const unsigned int* __restrict__ ws,
                                              float* __restrict__ out, int B) {
    __shared__ unsigned int s_u[4 * WSTRIDE];

    const int tid = threadIdx.x & 63;
    const int wid = threadIdx.x >> 6;
    const int b   = blockIdx.x * 4 + wid;
    if (b >= B) return;   // wave-uniform exit; no cross-wave deps anywhere
    const float* wsf = (const float*)ws;
    const int*   wsi = (const int*)ws;

    unsigned int* inrow = s_u + wid * WSTRIDE;   // [66]
    unsigned int* c1    = inrow + 66;            // [400]
    unsigned int* pb1   = c1 + 400;              // [100]
    unsigned int* pb2   = pb1 + 100;             // [16]

    // ---- pack input signs: one row (c,y) per lane ----
    for (int r = tid; r < 66; r += 64) {
        int c = r / 22, y = r - c*22;
        const float2* p = (const float2*)(x + ((size_t)b*3 + c)*484 + (size_t)y*22);
        unsigned int bits = 0;
        #pragma unroll
        for (int j = 0; j < 11; ++j) {
            float2 v = p[j];
            bits |= (v.x >= 0.f ? 1u : 0u) << (2*j);
            bits |= (v.y >= 0.f ? 1u : 0u) << (2*j+1);
        }
        inrow[r] = bits;
    }
    __builtin_amdgcn_wave_barrier();

    // ---- conv1 + BN sign: 3 VALU per (pos,och): xor, bcnt(acc=negthr), alignbit ----
    for (int pos = tid; pos < 400; pos += 64) {
        int y = pos / 20, xx = pos - y*20;
        unsigned int g = 0;
        #pragma unroll
        for (int c = 0; c < 3; ++c)
            #pragma unroll
            for (int dy = 0; dy < 3; ++dy)
                g |= ((inrow[c*22 + y + dy] >> xx) & 7u) << (c*9 + dy*3);
        unsigned int word = 0;
        #pragma unroll
        for (int o = 31; o >= 0; --o) {
            unsigned int s = (unsigned int)(__popc(g ^ ws[OFF_W1 + o]) + wsi[OFF_T1 + o]);
            word = __builtin_amdgcn_alignbit(word, s, 31);  // word=(word<<1)|(s>>31)
        }
        c1[pos] = word;
    }
    __builtin_amdgcn_wave_barrier();

    // ---- maxpool1 == OR of sign bits ----
    for (int p = tid; p < 100; p += 64) {
        int py = p / 10, px = p - py*10;
        int base = (2*py)*20 + 2*px;
        pb1[p] = c1[base] | c1[base+1] | c1[base+20] | c1[base+21];
    }
    __builtin_amdgcn_wave_barrier();

    // ---- conv2 + BN sign + pool2 (lane = one of 8x8 positions) ----
    {
        int y = tid >> 3, xx = tid & 7;
        unsigned int in9[9];
        #pragma unroll
        for (int dy = 0; dy < 3; ++dy)
            #pragma unroll
            for (int dx = 0; dx < 3; ++dx)
                in9[dy*3+dx] = pb1[(y+dy)*10 + xx + dx];
        unsigned int word = 0;
        #pragma unroll
        for (int o = 31; o >= 0; --o) {
            int s = wsi[OFF_T2 + o];
            #pragma unroll
            for (int k = 0; k < 9; ++k)
                s += __popc(in9[k] ^ ws[OFF_W2 + o*9 + k]);
            word = __builtin_amdgcn_alignbit(word, (unsigned int)s, 31);
        }
        word |= __shfl_xor(word, 1);   // pool across x pairs
        word |= __shfl_xor(word, 8);   // pool across y pairs
        if ((tid & 9) == 0)            // x even, y even
            pb2[(y>>1)*4 + (xx>>1)] = word;
    }
    __builtin_amdgcn_wave_barrier();

    // ---- conv3 + BN sign + pool3 -> 64-bit feature via ballot (lane = och) ----
    // OR of sign bits == sign bit of OR.
    unsigned long long b3 = 0;
    {
        unsigned int bb[16];
        #pragma unroll
        for (int i = 0; i < 16; ++i) bb[i] = pb2[i];
        unsigned int w3r[9];
        #pragma unroll
        for (int k = 0; k < 9; ++k) w3r[k] = ws[OFF_W3 + tid*9 + k];
        int negt = wsi[OFF_T3 + tid];
        unsigned int oracc = 0;
        #pragma unroll
        for (int py = 0; py < 2; ++py)
            #pragma unroll
            for (int px = 0; px < 2; ++px) {
                int s = negt;
                #pragma unroll
                for (int dy = 0; dy < 3; ++dy)
                    #pragma unroll
                    for (int dx = 0; dx < 3; ++dx)
                        s += __popc(bb[(py+dy)*4 + px + dx] ^ w3r[dy*3+dx]);
                oracc |= (unsigned int)s;
            }
        b3 = __ballot((int)oracc < 0);
    }

    // ---- fc1 in registers (outputs tid, tid+64 consumed by the same lane) ----
    float h0, h1;
    {
        const unsigned long long* wfc1b = (const unsigned long long*)(ws + OFF_WFC1);
        int pc0 = __popcll(b3 ^ wfc1b[tid]);
        int pc1 = __popcll(b3 ^ wfc1b[tid + 64]);
        float p0 = fmaf((float)pc0, wsf[OFF_A4 + tid],      wsf[OFF_C4 + tid]);
        float p1 = fmaf((float)pc1, wsf[OFF_A4 + tid + 64], wsf[OFF_C4 + tid + 64]);
        h0 = fminf(1.f, fmaxf(-1.f, p0));
        h1 = fminf(1.f, fmaxf(-1.f, p1));
    }

    // ---- fc2 (softmax) / fc3 (BN) ----
    {
        float part[6];
        #pragma unroll
        for (int j = 0; j < 2; ++j)
            part[j] = h0 * wsf[OFF_WF2 + j*128 + tid] + h1 * wsf[OFF_WF2 + j*128 + 64 + tid];
        #pragma unroll
        for (int j = 0; j < 4; ++j)
            part[2+j] = h0 * wsf[OFF_WF3 + j*128 + tid] + h1 * wsf[OFF_WF3 + j*128 + 64 + tid];
        #pragma unroll
        for (int off = 32; off; off >>= 1) {
            #pragma unroll
            for (int j = 0; j < 6; ++j)
                part[j] += __shfl_xor(part[j], off);
        }
        if (tid < 6) {
            if (tid < 2) {
                float y0 = part[0]*wsf[OFF_BN5+0] + wsf[OFF_BN5+2];
                float y1 = part[1]*wsf[OFF_BN5+1] + wsf[OFF_BN5+3];
                float mx = fmaxf(y0, y1);
                float e0 = expf(y0 - mx), e1 = expf(y1 - mx);
                float r  = 1.f / (e0 + e1);
                out[(size_t)b*2 + tid] = (tid == 0 ? e0 : e1) * r;
            } else {
                int j = tid - 2;
                out[(size_t)B*2 + (size_t)b*4 + j] = part[2+j]*wsf[OFF_BN6+j] + wsf[OFF_BN6+4+j];
            }
        }
    }
}

extern "C" void kernel_launch(void* const* d_in, const int* in_sizes, int n_in,
                              void* d_out, int out_size, void* d_ws, size_t ws_size,
                              hipStream_t stream) {
    const float* x    = (const float*)d_in[0];
    const float* w1   = (const float*)d_in[1];
    const float* w2   = (const float*)d_in[2];
    const float* w3   = (const float*)d_in[3];
    const float* wfc1 = (const float*)d_in[4];
    const float* wfc2 = (const float*)d_in[5];
    const float* wfc3 = (const float*)d_in[6];
    const float* bn1  = (const float*)d_in[7];
    const float* bn2  = (const float*)d_in[8];
    const float* bn3  = (const float*)d_in[9];
    const float* bn4  = (const float*)d_in[10];
    const float* bn5  = (const float*)d_in[11];
    const float* bn6  = (const float*)d_in[12];
    unsigned int* ws  = (unsigned int*)d_ws;
    float* out        = (float*)d_out;
    int B = in_sizes[0] / 1452;   // 3*22*22

    k_prep<<<5, 256, 0, stream>>>(w1, w2, w3, wfc1, wfc2, wfc3,
                                  bn1, bn2, bn3, bn4, bn5, bn6, ws);
    k_main<<<(B + 3) / 4, 256, 0, stream>>>(x, ws, out, B);
}